// Round 13
// baseline (106.121 us; speedup 1.0000x reference)
//
#include <hip/hip_runtime.h>

#define Wd 512
#define Hd 512
#define NIMG 48                      // 16 batch * 3 channels
#define RB 8                         // output rows per tile
#define LR (RB + 2)                  // staged rows incl. vertical halo
#define NBLK (NIMG * (Hd / RB))      // 48*64 = 3072 blocks, one tile each
#define ACC_STRIDE 16                // 64 acc cells spread 64 B apart
constexpr float INV_N = 1.0f / (float)((long long)NIMG * Hd * Wd);

// async global->LDS, 16 B per lane: HW writes lds_base + lane*16.
__device__ __forceinline__ void gload_lds16(const float* g, float* l) {
    __builtin_amdgcn_global_load_lds(
        (const __attribute__((address_space(1))) void*)g,
        (__attribute__((address_space(3))) void*)l, 16, 0, 0);
}

// Scharr on a 3x10 window; pixel j (0..7) uses cols j..j+2 of rows r0,r1,r2.
__device__ __forceinline__ float scharr_pix(const float r0[10], const float r1[10],
                                            const float r2[10], int j) {
    float tl = r0[j], tm = r0[j + 1], tr = r0[j + 2];
    float ml = r1[j],                  mr = r1[j + 2];
    float bl = r2[j], bm = r2[j + 1], br = r2[j + 2];
    float gx = 3.f * (tr - tl) + 10.f * (mr - ml) + 3.f * (br - bl);
    float gy = 3.f * (bl - tl) + 10.f * (bm - tm) + 3.f * (br - tr);
    return fabsf(gx) + fabsf(gy);
}

// Read cols [c0-1 .. c0+8] of one staged LDS row; halo via neighbor-lane shfl
// (wave spans the full 512-col row, lane edges == image edges -> zero).
__device__ __forceinline__ void lds_row(const float* __restrict__ row, int lane,
                                        float r[10]) {
    float4 b0 = *reinterpret_cast<const float4*>(row + lane * 8);
    float4 b1 = *reinterpret_cast<const float4*>(row + lane * 8 + 4);
    r[1] = b0.x; r[2] = b0.y; r[3] = b0.z; r[4] = b0.w;
    r[5] = b1.x; r[6] = b1.y; r[7] = b1.z; r[8] = b1.w;
    float lv = __shfl_up(b1.w, 1, 64);     // lane-1's col c0-1
    float rv = __shfl_down(b0.x, 1, 64);   // lane+1's col c0+8
    r[0] = (lane > 0)  ? lv : 0.f;
    r[9] = (lane < 63) ? rv : 0.f;
}

__global__ void __launch_bounds__(256, 4)
scharr_loss_kernel(const float* __restrict__ x, const float* __restrict__ gt,
                   float* __restrict__ acc, unsigned* __restrict__ counter,
                   float* __restrict__ out) {
    __shared__ float lb[2][LR][Wd];      // exactly 40 KB -> 4 blocks/CU

    int wid  = threadIdx.x >> 6;         // 0..3
    int lane = threadIdx.x & 63;

    // Bijective XCD swizzle (NBLK % 8 == 0): consecutive tiles of one image
    // land on the same XCD -> block-boundary halo rows are L2 hits.
    int b    = blockIdx.x;
    int swz  = (b & 7) * (NBLK / 8) + (b >> 3);
    int img  = swz >> 6;                 // 64 tiles per image
    int h0   = (swz & 63) * RB;

    const float* __restrict__ xb = x  + (size_t)img * Hd * Wd;
    const float* __restrict__ gb = gt + (size_t)img * Hd * Wd;

    // --- stage: 40 chunks of 1 KB (2 img x 10 rows x 2 halves), 10 per wave ---
    #pragma unroll
    for (int t = 0; t < 10; ++t) {
        int c    = wid + t * 4;          // 0..39, wave-uniform
        int im   = (c >= 20) ? 1 : 0;
        int cc   = c - im * 20;
        int row  = cc >> 1;
        int half = cc & 1;
        int gh   = h0 - 1 + row;
        const float* __restrict__ sb = im ? gb : xb;
        float* dst = &lb[im][row][half * 256];
        if ((unsigned)gh < (unsigned)Hd) {
            gload_lds16(sb + (size_t)gh * Wd + half * 256 + lane * 4, dst);
        } else {
            *reinterpret_cast<float4*>(dst + lane * 4) =
                make_float4(0.f, 0.f, 0.f, 0.f);
        }
    }
    __syncthreads();                     // single vmcnt(0) drain per block

    // --- compute: wave w owns local output rows 2w, 2w+1 ---
    int lr = wid * 2;
    float rx[3][10], rg[3][10];
    lds_row(&lb[0][lr][0],     lane, rx[0]);
    lds_row(&lb[0][lr + 1][0], lane, rx[1]);
    lds_row(&lb[1][lr][0],     lane, rg[0]);
    lds_row(&lb[1][lr + 1][0], lane, rg[1]);

    float sum = 0.f;
    #pragma unroll
    for (int i = 0; i < 2; ++i) {
        const int c0 = i % 3, c1 = (i + 1) % 3, c2 = (i + 2) % 3;
        lds_row(&lb[0][lr + i + 2][0], lane, rx[c2]);
        lds_row(&lb[1][lr + i + 2][0], lane, rg[c2]);
        #pragma unroll
        for (int j = 0; j < 8; ++j) {
            float a = scharr_pix(rx[c0], rx[c1], rx[c2], j);
            float g = scharr_pix(rg[c0], rg[c1], rg[c2], j);
            sum += fabsf(a - g);
        }
    }

    // wave reduce; cross-wave partials reuse lb (keeps LDS at exactly 40 KB)
    #pragma unroll
    for (int off = 32; off > 0; off >>= 1)
        sum += __shfl_down(sum, off, 64);
    __syncthreads();                     // all waves done reading lb
    if (lane == 0) lb[0][0][wid] = sum;
    __syncthreads();

    // --- fused finalize: spread atomics + last-block-done reduction ---
    if (threadIdx.x == 0) {
        float s = lb[0][0][0] + lb[0][0][1] + lb[0][0][2] + lb[0][0][3];
        atomicAdd(&acc[(b & 63) * ACC_STRIDE], s);   // agent-scope by default
        unsigned t = __hip_atomic_fetch_add(counter, 1u, __ATOMIC_ACQ_REL,
                                            __HIP_MEMORY_SCOPE_AGENT);
        lb[0][0][8] = (t == NBLK - 1) ? 1.f : 0.f;
    }
    __syncthreads();
    if (lb[0][0][8] != 0.f && threadIdx.x < 64) {
        // release-sequence on counter => all blocks' acc adds visible
        float v = __hip_atomic_load(&acc[threadIdx.x * ACC_STRIDE],
                                    __ATOMIC_ACQUIRE, __HIP_MEMORY_SCOPE_AGENT);
        #pragma unroll
        for (int off = 32; off > 0; off >>= 1)
            v += __shfl_down(v, off, 64);
        if (threadIdx.x == 0)
            out[0] = v * INV_N;
    }
}

extern "C" void kernel_launch(void* const* d_in, const int* in_sizes, int n_in,
                              void* d_out, int out_size, void* d_ws, size_t ws_size,
                              hipStream_t stream) {
    const float* x  = (const float*)d_in[0];
    const float* gt = (const float*)d_in[1];
    float* out      = (float*)d_out;
    float* acc      = (float*)d_ws;                          // 64 cells, 64 B apart
    unsigned* counter = (unsigned*)((char*)d_ws + 64 * ACC_STRIDE * 4);

    // zero acc cells + counter every call (graph-safe async memset node)
    hipMemsetAsync(d_ws, 0, 64 * ACC_STRIDE * 4 + 4, stream);

    scharr_loss_kernel<<<NBLK, 256, 0, stream>>>(x, gt, acc, counter, out);
}